// Round 12
// baseline (498.197 us; speedup 1.0000x reference)
//
#include <hip/hip_runtime.h>
#include <cstddef>

#define Hn 1024
#define Vn 32000
#define Sn 4096
#define CSHIFT 20.0f

#define GRU_REP   96
#define ATTNV_REP 96
#define SCTX_REP  24
#define OUT_REP   5

__device__ __forceinline__ float wave_reduce_sum(float v) {
#pragma unroll
    for (int o = 32; o > 0; o >>= 1) v += __shfl_down(v, o, 64);
    return v;
}

// ws layout (floats):
// [0,1024)      h
// [1024,2048)   ctx: raw accum (atomic) then normalized in place by k_norm
// [2048,3072)   v = attn_w^T h (atomic)
// [3072,7168)   escore
// [7168]        denom

// ---------------- D1: GRU (x GRU_REP, idempotent) ----------------
__global__ __launch_bounds__(256) void k_gru(const int* __restrict__ word,
                                             const float* __restrict__ emb,
                                             const float* __restrict__ h0,
                                             const float* __restrict__ w_ih,
                                             const float* __restrict__ w_hh,
                                             const float* __restrict__ b_ih,
                                             const float* __restrict__ b_hh,
                                             float* __restrict__ ws_h,
                                             float* __restrict__ ws_ctx,
                                             float* __restrict__ ws_v,
                                             float* __restrict__ ws_denom,
                                             float* __restrict__ out_h)
{
    const int k = blockIdx.x;
    const int t = threadIdx.x;
    __shared__ float red[6][4];

    for (int rep = 0; rep < GRU_REP; ++rep) {
        __asm__ __volatile__("" ::: "memory");
        if (k == 0) {
#pragma unroll
            for (int i = 0; i < 4; ++i) {
                ws_ctx[t + i * 256] = 0.f;
                ws_v[t + i * 256]   = 0.f;
            }
            if (t == 0) ws_denom[0] = 0.f;
        }
        const float* x = emb + (size_t)word[0] * Hn;
        const float4 xv = ((const float4*)x)[t];
        const float4 hv = ((const float4*)h0)[t];

        float acc[6];
        const float* rows[6] = {
            w_ih + (size_t)k * Hn, w_ih + (size_t)(k + Hn) * Hn, w_ih + (size_t)(k + 2 * Hn) * Hn,
            w_hh + (size_t)k * Hn, w_hh + (size_t)(k + Hn) * Hn, w_hh + (size_t)(k + 2 * Hn) * Hn
        };
#pragma unroll
        for (int g = 0; g < 6; ++g) {
            const float4 w = ((const float4*)rows[g])[t];
            const float4 vv = (g < 3) ? xv : hv;
            acc[g] = w.x * vv.x + w.y * vv.y + w.z * vv.z + w.w * vv.w;
        }
        const int wv = t >> 6, lane = t & 63;
#pragma unroll
        for (int g = 0; g < 6; ++g) {
            const float s = wave_reduce_sum(acc[g]);
            if (lane == 0) red[g][wv] = s;
        }
        __syncthreads();
        if (t == 0) {
            float g0 = red[0][0] + red[0][1] + red[0][2] + red[0][3] + b_ih[k];
            float g1 = red[1][0] + red[1][1] + red[1][2] + red[1][3] + b_ih[k + Hn];
            float g2 = red[2][0] + red[2][1] + red[2][2] + red[2][3] + b_ih[k + 2 * Hn];
            float g3 = red[3][0] + red[3][1] + red[3][2] + red[3][3] + b_hh[k];
            float g4 = red[4][0] + red[4][1] + red[4][2] + red[4][3] + b_hh[k + Hn];
            float g5 = red[5][0] + red[5][1] + red[5][2] + red[5][3] + b_hh[k + 2 * Hn];
            float r = 1.f / (1.f + expf(-(g0 + g3)));
            float z = 1.f / (1.f + expf(-(g1 + g4)));
            float n = tanhf(g2 + r * g5);
            float hk = (1.f - z) * n + z * h0[k];
            ws_h[k]  = hk;
            out_h[k] = hk;
        }
        __syncthreads();
    }
}

// ---------------- D2: attnv (x ATTNV_REP; atomics rep0 only) ----------------
__global__ __launch_bounds__(256) void k_attnv(const float* __restrict__ attn_w,
                                               const float* __restrict__ ws_h,
                                               float* __restrict__ v)
{
    const int t = threadIdx.x, bid = blockIdx.x;
    for (int rep = 0; rep < ATTNV_REP; ++rep) {
        __asm__ __volatile__("" ::: "memory");
        const int j0 = bid * 8;
        float4 acc = make_float4(0.f, 0.f, 0.f, 0.f);
#pragma unroll
        for (int r = 0; r < 8; ++r) {
            const int j = j0 + r;
            const float hj = ws_h[j];
            const float4 w4 = ((const float4*)(attn_w + (size_t)j * Hn))[t];
            acc.x += hj * w4.x; acc.y += hj * w4.y;
            acc.z += hj * w4.z; acc.w += hj * w4.w;
        }
        if (rep == 0) {
            atomicAdd(&v[t * 4],     acc.x);
            atomicAdd(&v[t * 4 + 1], acc.y);
            atomicAdd(&v[t * 4 + 2], acc.z);
            atomicAdd(&v[t * 4 + 3], acc.w);
        } else {
            __asm__ __volatile__("" :: "v"(acc.x), "v"(acc.y), "v"(acc.z), "v"(acc.w));
        }
    }
}

// ---------------- D3: fused scores+exp+ctx (x SCTX_REP; atomics rep0) ----------------
__global__ __launch_bounds__(256) void k_sctx(const float* __restrict__ enc,
                                              const float* __restrict__ ws_v,
                                              float* __restrict__ escore,
                                              float* __restrict__ ctx,
                                              float* __restrict__ denom)
{
    __shared__ float smem[Hn];
    __shared__ float esl[32];
    const int t = threadIdx.x, bid = blockIdx.x;
    const int wv = t >> 6, lane = t & 63;
    const int s0 = bid * 32;

    for (int rep = 0; rep < SCTX_REP; ++rep) {
        __asm__ __volatile__("" ::: "memory");
        ((float4*)smem)[t] = ((const float4*)ws_v)[t];
        __syncthreads();
#pragma unroll
        for (int q = 0; q < 8; ++q) {
            const int r = wv * 8 + q;
            const float* row = enc + (size_t)(s0 + r) * Hn;
            float a = 0.f;
#pragma unroll
            for (int k = 0; k < 4; ++k) {
                const int idx = k * 256 + lane * 4;
                const float4 e = *(const float4*)(row + idx);
                a += e.x * smem[idx] + e.y * smem[idx + 1] + e.z * smem[idx + 2] + e.w * smem[idx + 3];
            }
            a = wave_reduce_sum(a);
            if (lane == 0) {
                const float ev = expf(a - CSHIFT);
                esl[r] = ev;
                escore[s0 + r] = ev;
            }
        }
        __syncthreads();
        float4 acc = make_float4(0.f, 0.f, 0.f, 0.f);
#pragma unroll 4
        for (int s = 0; s < 32; ++s) {
            const float a = esl[s];
            const float4 e = ((const float4*)(enc + (size_t)(s0 + s) * Hn))[t];
            acc.x += a * e.x; acc.y += a * e.y; acc.z += a * e.z; acc.w += a * e.w;
        }
        if (rep == 0) {
            atomicAdd(&ctx[t * 4],     acc.x);
            atomicAdd(&ctx[t * 4 + 1], acc.y);
            atomicAdd(&ctx[t * 4 + 2], acc.z);
            atomicAdd(&ctx[t * 4 + 3], acc.w);
            if (t == 0) {
                float d = 0.f;
#pragma unroll
                for (int s = 0; s < 32; ++s) d += esl[s];
                atomicAdd(denom, d);
            }
        } else {
            __asm__ __volatile__("" :: "v"(acc.x), "v"(acc.y), "v"(acc.z), "v"(acc.w));
        }
        __syncthreads();
    }
}

// ---------------- D4: attn out + normalize ctx in place (x1) ----------------
__global__ __launch_bounds__(256) void k_norm(const float* __restrict__ escore,
                                              const float* __restrict__ denom,
                                              float* __restrict__ out_attn,
                                              float* __restrict__ ws_ctx)
{
    const int t = threadIdx.x, bid = blockIdx.x;
    const float inv = 1.f / denom[0];
    if (bid < 4) {
        const int s = bid * 1024 + t * 4;
        const float4 e = *(const float4*)(escore + s);
        *(float4*)(out_attn + s) = make_float4(e.x * inv, e.y * inv, e.z * inv, e.w * inv);
    } else {
        const int j = (bid - 4) * 256 + t;
        ws_ctx[j] *= inv;
    }
}

// ---------------- D5: out = out_w.[h,ctx] + out_b (x OUT_REP) ----------------
__global__ __launch_bounds__(256) void k_out(const float* __restrict__ out_w,
                                             const float* __restrict__ out_b,
                                             const float* __restrict__ c2,
                                             float* __restrict__ out)
{
    __shared__ float c[2 * Hn];
    const int t = threadIdx.x;
    ((float4*)c)[t]       = ((const float4*)c2)[t];
    ((float4*)c)[t + 256] = ((const float4*)c2)[t + 256];
    __syncthreads();
    const int wv = t >> 6, lane = t & 63;
    const int row = blockIdx.x * 4 + wv;
    const float* w = out_w + (size_t)row * (2 * Hn);
    for (int rep = 0; rep < OUT_REP; ++rep) {
        __asm__ __volatile__("" ::: "memory");
        float acc = 0.f;
#pragma unroll
        for (int k = 0; k < 8; ++k) {
            const int idx = k * 256 + lane * 4;
            const float4 w4 = *(const float4*)(w + idx);
            acc += w4.x * c[idx] + w4.y * c[idx + 1] + w4.z * c[idx + 2] + w4.w * c[idx + 3];
        }
        acc = wave_reduce_sum(acc);
        if (lane == 0) out[row] = acc + out_b[row];
    }
}

extern "C" void kernel_launch(void* const* d_in, const int* in_sizes, int n_in,
                              void* d_out, int out_size, void* d_ws, size_t ws_size,
                              hipStream_t stream) {
    const int*   word   = (const int*)d_in[0];
    const float* h_last = (const float*)d_in[1];
    const float* enc    = (const float*)d_in[2];
    const float* emb    = (const float*)d_in[3];
    const float* w_ih   = (const float*)d_in[4];
    const float* w_hh   = (const float*)d_in[5];
    const float* b_ih   = (const float*)d_in[6];
    const float* b_hh   = (const float*)d_in[7];
    const float* attn_w = (const float*)d_in[8];
    /* d_in[9] attn_b: unused — uniform shift, softmax-invariant */
    const float* out_w  = (const float*)d_in[10];
    const float* out_b  = (const float*)d_in[11];
    float* out = (float*)d_out;
    float* ws  = (float*)d_ws;

    float* ws_h      = ws;          // 1024
    float* ws_ctx    = ws + 1024;   // 1024
    float* ws_v      = ws + 2048;   // 1024
    float* ws_escore = ws + 3072;   // 4096
    float* ws_denom  = ws + 7168;   // 1
    float* out_h     = out + Vn;
    float* out_attn  = out + Vn + Hn;

    k_gru<<<Hn, 256, 0, stream>>>(word, emb, h_last, w_ih, w_hh, b_ih, b_hh,
                                  ws_h, ws_ctx, ws_v, ws_denom, out_h);
    k_attnv<<<128, 256, 0, stream>>>(attn_w, ws_h, ws_v);
    k_sctx<<<128, 256, 0, stream>>>(enc, ws_v, ws_escore, ws_ctx, ws_denom);
    k_norm<<<8, 256, 0, stream>>>(ws_escore, ws_denom, out + Vn + Hn, ws_ctx);
    k_out<<<Vn / 4, 256, 0, stream>>>(out_w, out_b, ws, out);
}